// Round 10
// baseline (736.968 us; speedup 1.0000x reference)
//
#include <hip/hip_runtime.h>
#include <hip/hip_cooperative_groups.h>

namespace cg = cooperative_groups;

#define N_FEAT 128
#define N_CLS 64
#define GRID 1024
#define TPB 256

// ---------------- fused cooperative pipeline ----------------
// phases: zero deg | rank | block-scan deg | scan bsum | off/nrm | scatter+gemm | agg
__global__ __launch_bounds__(TPB, 4) void k_fused(
    const float* __restrict__ X, const float* __restrict__ W, const float* __restrict__ b,
    const int* __restrict__ src, const int* __restrict__ dst, int n, int ne,
    int* __restrict__ deg, int* __restrict__ rank, int* __restrict__ offtmp,
    int* __restrict__ off, int* __restrict__ bsum, int* __restrict__ esrc,
    float* __restrict__ nrm, float* __restrict__ Y, float* __restrict__ out) {
    cg::grid_group grid = cg::this_grid();
    __shared__ int sm[TPB];
    const int t = threadIdx.x;
    const int tid = blockIdx.x * TPB + t;
    const int nth = gridDim.x * TPB;
    const int G = gridDim.x;

    // phase 0: zero deg
    for (int i = tid; i < n; i += nth) deg[i] = 0;
    grid.sync();

    // phase 1: degree + per-edge rank (1 atomic/edge, coalesced rank store)
    for (int i = tid; i < ne; i += nth) rank[i] = atomicAdd(&deg[dst[i]], 1);
    grid.sync();

    // phase 2a: per-block scan of a contiguous chunk of deg (chunk <= 256 for n <= 65536)
    const int chunk = (n + G - 1) / G;
    {
        int idx = blockIdx.x * chunk + t;
        int v = (t < chunk && idx < n) ? deg[idx] : 0;
        sm[t] = v;
        __syncthreads();
        for (int d = 1; d < TPB; d <<= 1) {
            int u = (t >= d) ? sm[t - d] : 0;
            __syncthreads();
            sm[t] += u;
            __syncthreads();
        }
        if (t < chunk && idx < n) offtmp[idx] = sm[t] - v;  // exclusive within block
        if (t == TPB - 1) bsum[blockIdx.x] = sm[TPB - 1];
    }
    grid.sync();

    // phase 2b: block 0 exclusive-scans bsum[G] (P entries/thread, P<=8)
    if (blockIdx.x == 0) {
        const int P = (G + TPB - 1) / TPB;
        int loc[8];
        int base = t * P;
        int tot = 0;
#pragma unroll
        for (int j = 0; j < 8; ++j) {
            int idx = base + j;
            int v = (j < P && idx < G) ? bsum[idx] : 0;
            loc[j] = v;
            tot += v;
        }
        sm[t] = tot;
        __syncthreads();
        for (int d = 1; d < TPB; d <<= 1) {
            int u = (t >= d) ? sm[t - d] : 0;
            __syncthreads();
            sm[t] += u;
            __syncthreads();
        }
        int run = sm[t] - tot;
#pragma unroll
        for (int j = 0; j < 8; ++j) {
            int idx = base + j;
            if (j < P && idx < G) {
                bsum[idx] = run;
                run += loc[j];
            }
        }
    }
    grid.sync();

    // phase 2c: off = offtmp + bsum[block]; nrm = rsqrt(max(deg,1))
    for (int i = tid; i < n; i += nth) {
        off[i] = offtmp[i] + bsum[i / chunk];
        nrm[i] = rsqrtf(fmaxf((float)deg[i], 1.0f));
    }
    if (tid == 0) off[n] = ne;
    grid.sync();

    // phase 3a: atomic-free scatter (needs off, rank)
    for (int i = tid; i < ne; i += nth) esrc[off[dst[i]] + rank[i]] = src[i];

    // phase 3b: gemm (needs nrm; independent of scatter, no sync between)
    {
        int lane = t & 63;
        int q = __builtin_amdgcn_readfirstlane(t >> 6);  // wave id 0..3
        int cq = q * 16;
        const float* wq = W + cq;
        int nblk = (n + 63) >> 6;
        for (int blk = blockIdx.x; blk < nblk; blk += G) {
            int node = blk * 64 + lane;
            if (node < n) {
                float acc[16];
#pragma unroll
                for (int c = 0; c < 16; ++c) acc[c] = 0.f;
                const float* xrow = X + (size_t)node * N_FEAT;
                for (int k4 = 0; k4 < N_FEAT; k4 += 4) {
                    float4 xv = *(const float4*)(xrow + k4);
#pragma unroll
                    for (int j = 0; j < 4; ++j) {
                        float xj = (j == 0) ? xv.x : (j == 1) ? xv.y : (j == 2) ? xv.z : xv.w;
                        const float* wrow = wq + (size_t)(k4 + j) * N_CLS;  // wave-uniform
#pragma unroll
                        for (int c = 0; c < 16; c += 4) {
                            float4 wv = *(const float4*)(wrow + c);
                            acc[c + 0] = fmaf(xj, wv.x, acc[c + 0]);
                            acc[c + 1] = fmaf(xj, wv.y, acc[c + 1]);
                            acc[c + 2] = fmaf(xj, wv.z, acc[c + 2]);
                            acc[c + 3] = fmaf(xj, wv.w, acc[c + 3]);
                        }
                    }
                }
                float nv = nrm[node];
                float* yrow = Y + (size_t)node * N_CLS + cq;
#pragma unroll
                for (int c = 0; c < 16; c += 4) {
                    float4 o;
                    o.x = acc[c + 0] * nv;
                    o.y = acc[c + 1] * nv;
                    o.z = acc[c + 2] * nv;
                    o.w = acc[c + 3] * nv;
                    *(float4*)(yrow + c) = o;
                }
            }
        }
    }
    grid.sync();

    // phase 4: wave-per-dst gather (4 edge-slots x 16 lanes, float4/lane, unroll x2)
    {
        int lane = t & 63;
        int g = lane >> 4;
        int c = (lane & 15) * 4;
        int gw = tid >> 6;
        int nw = nth >> 6;
        for (int wid = gw; wid < n; wid += nw) {
            int s = off[wid];
            int e = off[wid + 1];
            float4 a0 = make_float4(0.f, 0.f, 0.f, 0.f);
            float4 a1 = make_float4(0.f, 0.f, 0.f, 0.f);
            int p = s + g;
            for (; p + 4 < e; p += 8) {
                int s0 = esrc[p];
                int s1 = esrc[p + 4];
                float4 r0 = *(const float4*)(Y + (size_t)s0 * N_CLS + c);
                float4 r1 = *(const float4*)(Y + (size_t)s1 * N_CLS + c);
                a0.x += r0.x; a0.y += r0.y; a0.z += r0.z; a0.w += r0.w;
                a1.x += r1.x; a1.y += r1.y; a1.z += r1.z; a1.w += r1.w;
            }
            if (p < e) {
                int s0 = esrc[p];
                float4 r0 = *(const float4*)(Y + (size_t)s0 * N_CLS + c);
                a0.x += r0.x; a0.y += r0.y; a0.z += r0.z; a0.w += r0.w;
            }
            a0.x += a1.x; a0.y += a1.y; a0.z += a1.z; a0.w += a1.w;
#pragma unroll
            for (int m = 16; m <= 32; m <<= 1) {
                a0.x += __shfl_xor(a0.x, m);
                a0.y += __shfl_xor(a0.y, m);
                a0.z += __shfl_xor(a0.z, m);
                a0.w += __shfl_xor(a0.w, m);
            }
            if (lane < 16) {
                float nv = nrm[wid];
                float4 bv = *(const float4*)(b + c);
                float4 o;
                o.x = a0.x * nv + bv.x;
                o.y = a0.y * nv + bv.y;
                o.z = a0.z * nv + bv.z;
                o.w = a0.w * nv + bv.w;
                *(float4*)(out + (size_t)wid * N_CLS + c) = o;
            }
        }
    }
}

// ---------------- fallback multi-kernel path (round-9, proven) ----------------
__global__ __launch_bounds__(256) void k_zero(int4* __restrict__ p, int n4) {
    int i = blockIdx.x * blockDim.x + threadIdx.x;
    if (i < n4) p[i] = make_int4(0, 0, 0, 0);
}

__global__ __launch_bounds__(256) void k_rank(const int* __restrict__ dst, int ne,
                                              int* __restrict__ deg, int* __restrict__ rank) {
    int i = blockIdx.x * blockDim.x + threadIdx.x;
    if (i < ne) rank[i] = atomicAdd(&deg[dst[i]], 1);
}

__global__ __launch_bounds__(256) void k_scan1(const int* __restrict__ deg, int n,
                                               int* __restrict__ offtmp, int* __restrict__ bsum) {
    __shared__ int s[256];
    int t = threadIdx.x;
    int i = blockIdx.x * 256 + t;
    int v = (i < n) ? deg[i] : 0;
    s[t] = v;
    __syncthreads();
    for (int d = 1; d < 256; d <<= 1) {
        int u = (t >= d) ? s[t - d] : 0;
        __syncthreads();
        s[t] += u;
        __syncthreads();
    }
    if (i < n) offtmp[i] = s[t] - v;
    if (t == 255) bsum[blockIdx.x] = s[255];
}

__global__ __launch_bounds__(1024) void k_scan2(int* __restrict__ bsum, int nb) {
    __shared__ int s[1024];
    int t = threadIdx.x;
    int v = (t < nb) ? bsum[t] : 0;
    s[t] = v;
    __syncthreads();
    for (int d = 1; d < 1024; d <<= 1) {
        int u = (t >= d) ? s[t - d] : 0;
        __syncthreads();
        s[t] += u;
        __syncthreads();
    }
    if (t < nb) bsum[t] = s[t] - v;
}

__global__ __launch_bounds__(256) void k_scan3(const int* __restrict__ deg,
                                               const int* __restrict__ offtmp,
                                               const int* __restrict__ bsum, int n, int ne,
                                               int* __restrict__ off, float* __restrict__ nrm) {
    int i = blockIdx.x * 256 + threadIdx.x;
    if (i < n) {
        off[i] = offtmp[i] + bsum[blockIdx.x];
        nrm[i] = rsqrtf(fmaxf((float)deg[i], 1.0f));
    }
    if (i == 0) off[n] = ne;
}

__global__ __launch_bounds__(256) void k_scatter(const int* __restrict__ src,
                                                 const int* __restrict__ dst,
                                                 const int* __restrict__ rank, int ne,
                                                 const int* __restrict__ off,
                                                 int* __restrict__ esrc) {
    int i = blockIdx.x * blockDim.x + threadIdx.x;
    if (i < ne) esrc[off[dst[i]] + rank[i]] = src[i];
}

__global__ __launch_bounds__(256) void k_gemm(const float* __restrict__ X,
                                              const float* __restrict__ W,
                                              const float* __restrict__ nrm,
                                              float* __restrict__ Y, int n) {
    int lane = threadIdx.x & 63;
    int q = __builtin_amdgcn_readfirstlane(threadIdx.x >> 6);
    int cq = q * 16;
    int node = blockIdx.x * 64 + lane;
    if (node >= n) return;
    float acc[16];
#pragma unroll
    for (int c = 0; c < 16; ++c) acc[c] = 0.f;
    const float* xrow = X + (size_t)node * N_FEAT;
    const float* wq = W + cq;
    for (int k4 = 0; k4 < N_FEAT; k4 += 4) {
        float4 xv = *(const float4*)(xrow + k4);
#pragma unroll
        for (int j = 0; j < 4; ++j) {
            float xj = (j == 0) ? xv.x : (j == 1) ? xv.y : (j == 2) ? xv.z : xv.w;
            const float* wrow = wq + (size_t)(k4 + j) * N_CLS;
#pragma unroll
            for (int c = 0; c < 16; c += 4) {
                float4 wv = *(const float4*)(wrow + c);
                acc[c + 0] = fmaf(xj, wv.x, acc[c + 0]);
                acc[c + 1] = fmaf(xj, wv.y, acc[c + 1]);
                acc[c + 2] = fmaf(xj, wv.z, acc[c + 2]);
                acc[c + 3] = fmaf(xj, wv.w, acc[c + 3]);
            }
        }
    }
    float nv = nrm[node];
    float* yrow = Y + (size_t)node * N_CLS + cq;
#pragma unroll
    for (int c = 0; c < 16; c += 4) {
        float4 o;
        o.x = acc[c + 0] * nv;
        o.y = acc[c + 1] * nv;
        o.z = acc[c + 2] * nv;
        o.w = acc[c + 3] * nv;
        *(float4*)(yrow + c) = o;
    }
}

__global__ __launch_bounds__(256) void k_agg(const int* __restrict__ off,
                                             const int* __restrict__ esrc,
                                             const float* __restrict__ Y,
                                             const float* __restrict__ nrm,
                                             const float* __restrict__ b,
                                             float* __restrict__ out, int n) {
    int wid = (int)((blockIdx.x * (size_t)blockDim.x + threadIdx.x) >> 6);
    if (wid >= n) return;
    int lane = threadIdx.x & 63;
    int g = lane >> 4;
    int c = (lane & 15) * 4;
    int s = off[wid];
    int e = off[wid + 1];
    float4 a0 = make_float4(0.f, 0.f, 0.f, 0.f);
    float4 a1 = make_float4(0.f, 0.f, 0.f, 0.f);
    int p = s + g;
    for (; p + 4 < e; p += 8) {
        int s0 = esrc[p];
        int s1 = esrc[p + 4];
        float4 r0 = *(const float4*)(Y + (size_t)s0 * N_CLS + c);
        float4 r1 = *(const float4*)(Y + (size_t)s1 * N_CLS + c);
        a0.x += r0.x; a0.y += r0.y; a0.z += r0.z; a0.w += r0.w;
        a1.x += r1.x; a1.y += r1.y; a1.z += r1.z; a1.w += r1.w;
    }
    if (p < e) {
        int s0 = esrc[p];
        float4 r0 = *(const float4*)(Y + (size_t)s0 * N_CLS + c);
        a0.x += r0.x; a0.y += r0.y; a0.z += r0.z; a0.w += r0.w;
    }
    a0.x += a1.x; a0.y += a1.y; a0.z += a1.z; a0.w += a1.w;
#pragma unroll
    for (int m = 16; m <= 32; m <<= 1) {
        a0.x += __shfl_xor(a0.x, m);
        a0.y += __shfl_xor(a0.y, m);
        a0.z += __shfl_xor(a0.z, m);
        a0.w += __shfl_xor(a0.w, m);
    }
    if (lane < 16) {
        float nv = nrm[wid];
        float4 bv = *(const float4*)(b + c);
        float4 o;
        o.x = a0.x * nv + bv.x;
        o.y = a0.y * nv + bv.y;
        o.z = a0.z * nv + bv.z;
        o.w = a0.w * nv + bv.w;
        *(float4*)(out + (size_t)wid * N_CLS + c) = o;
    }
}

extern "C" void kernel_launch(void* const* d_in, const int* in_sizes, int n_in,
                              void* d_out, int out_size, void* d_ws, size_t ws_size,
                              hipStream_t stream) {
    const float* X = (const float*)d_in[0];
    const float* W = (const float*)d_in[1];
    const float* b = (const float*)d_in[2];
    const int* src = (const int*)d_in[3];
    const int* dst = (const int*)d_in[4];
    int n = in_sizes[0] / N_FEAT;
    int ne = in_sizes[3];
    float* out = (float*)d_out;

    char* w = (char*)d_ws;
    auto take = [&](size_t bytes) {
        char* p = w;
        w += (bytes + 255) & ~(size_t)255;
        return p;
    };
    int nb = (n + 255) / 256;
    int* deg = (int*)take(((size_t)n + 4) * 4);
    int* off = (int*)take((size_t)(n + 1) * 4);
    int* rank = (int*)take((size_t)ne * 4);
    int* offtmp = (int*)take((size_t)n * 4);
    int* bsum = (int*)take((size_t)(GRID > 1024 ? GRID : 1024) * 4);
    int* esrc = (int*)take((size_t)ne * 4);
    float* nrm = (float*)take((size_t)n * 4);
    float* Y = (float*)take((size_t)n * N_CLS * 4);

    void* args[] = {(void*)&X,   (void*)&W,    (void*)&b,      (void*)&src,  (void*)&dst,
                    (void*)&n,   (void*)&ne,   (void*)&deg,    (void*)&rank, (void*)&offtmp,
                    (void*)&off, (void*)&bsum, (void*)&esrc,   (void*)&nrm,  (void*)&Y,
                    (void*)&out};
    hipError_t err = hipLaunchCooperativeKernel((const void*)k_fused, dim3(GRID), dim3(TPB),
                                                args, 0, stream);
    if (err != hipSuccess) {
        // fallback: proven round-9 multi-kernel pipeline (identical outputs)
        const int tb = 256;
        int n4 = (n + 3) / 4;
        k_zero<<<(n4 + tb - 1) / tb, tb, 0, stream>>>((int4*)deg, n4);
        k_rank<<<(ne + tb - 1) / tb, tb, 0, stream>>>(dst, ne, deg, rank);
        k_scan1<<<nb, 256, 0, stream>>>(deg, n, offtmp, bsum);
        k_scan2<<<1, 1024, 0, stream>>>(bsum, nb);
        k_scan3<<<nb, 256, 0, stream>>>(deg, offtmp, bsum, n, ne, off, nrm);
        k_scatter<<<(ne + tb - 1) / tb, tb, 0, stream>>>(src, dst, rank, ne, off, esrc);
        int gemm_blocks = (n + 63) / 64;
        k_gemm<<<gemm_blocks, 256, 0, stream>>>(X, W, nrm, Y, n);
        long long total_threads = (long long)n * 64;
        k_agg<<<(int)((total_threads + tb - 1) / tb), tb, 0, stream>>>(off, esrc, Y, nrm, b,
                                                                       out, n);
    }
}

// Round 11
// 112.815 us; speedup vs baseline: 6.5326x; 6.5326x over previous
//
#include <hip/hip_runtime.h>

#define N_FEAT 128
#define N_CLS 64

// 0) zero deg (runtime fillBuffer costs 43us for 200KB; this is ~2us)
__global__ __launch_bounds__(256) void k_zero(int4* __restrict__ p, int n4) {
    int i = blockIdx.x * blockDim.x + threadIdx.x;
    if (i < n4) p[i] = make_int4(0, 0, 0, 0);
}

// 1) FUSED: blocks [0, gemm_blocks) compute Yraw = X @ W (no nrm -> independent
//    of preprocessing); blocks [gemm_blocks, ...) do degree+rank (1 atomic/edge).
//    VALU-bound GEMM waves and latency-bound atomic waves co-schedule on the CUs.
__global__ __launch_bounds__(256) void k_gemm_rank(
    const float* __restrict__ X, const float* __restrict__ W, float* __restrict__ Y, int n,
    const int* __restrict__ dst, int ne, int* __restrict__ deg, int* __restrict__ rank,
    int gemm_blocks) {
    if ((int)blockIdx.x < gemm_blocks) {
        // ---- GEMM: block = 4 waves; wave = 16-col quarter (wave-uniform ->
        //      W addresses SGPR-derived -> s_load K$ broadcast). lane = node.
        int lane = threadIdx.x & 63;
        int q = __builtin_amdgcn_readfirstlane(threadIdx.x >> 6);  // wave 0..3
        int cq = q * 16;
        int node = blockIdx.x * 64 + lane;
        if (node >= n) return;

        float acc[16];
#pragma unroll
        for (int c = 0; c < 16; ++c) acc[c] = 0.f;

        const float* xrow = X + (size_t)node * N_FEAT;
        const float* wq = W + cq;
        for (int k4 = 0; k4 < N_FEAT; k4 += 4) {
            float4 xv = *(const float4*)(xrow + k4);
#pragma unroll
            for (int j = 0; j < 4; ++j) {
                float xj = (j == 0) ? xv.x : (j == 1) ? xv.y : (j == 2) ? xv.z : xv.w;
                const float* wrow = wq + (size_t)(k4 + j) * N_CLS;  // wave-uniform
#pragma unroll
                for (int c = 0; c < 16; c += 4) {
                    float4 wv = *(const float4*)(wrow + c);
                    acc[c + 0] = fmaf(xj, wv.x, acc[c + 0]);
                    acc[c + 1] = fmaf(xj, wv.y, acc[c + 1]);
                    acc[c + 2] = fmaf(xj, wv.z, acc[c + 2]);
                    acc[c + 3] = fmaf(xj, wv.w, acc[c + 3]);
                }
            }
        }

        float* yrow = Y + (size_t)node * N_CLS + cq;
#pragma unroll
        for (int c = 0; c < 16; c += 4) {
            float4 o;
            o.x = acc[c + 0];
            o.y = acc[c + 1];
            o.z = acc[c + 2];
            o.w = acc[c + 3];
            *(float4*)(yrow + c) = o;
        }
    } else {
        // ---- rank: degree histogram + per-edge rank (coalesced rank store)
        int i = ((int)blockIdx.x - gemm_blocks) * 256 + threadIdx.x;
        if (i < ne) rank[i] = atomicAdd(&deg[dst[i]], 1);
    }
}

// 2a) per-block exclusive scan of deg (256 elems/block), emit block sums
__global__ __launch_bounds__(256) void k_scan1(const int* __restrict__ deg, int n,
                                               int* __restrict__ offtmp, int* __restrict__ bsum) {
    __shared__ int s[256];
    int t = threadIdx.x;
    int i = blockIdx.x * 256 + t;
    int v = (i < n) ? deg[i] : 0;
    s[t] = v;
    __syncthreads();
    for (int d = 1; d < 256; d <<= 1) {
        int u = (t >= d) ? s[t - d] : 0;
        __syncthreads();
        s[t] += u;
        __syncthreads();
    }
    if (i < n) offtmp[i] = s[t] - v;  // exclusive
    if (t == 255) bsum[blockIdx.x] = s[255];
}

// 2b) single tiny block: exclusive scan of block sums (nb <= 1024)
__global__ __launch_bounds__(1024) void k_scan2(int* __restrict__ bsum, int nb) {
    __shared__ int s[1024];
    int t = threadIdx.x;
    int v = (t < nb) ? bsum[t] : 0;
    s[t] = v;
    __syncthreads();
    for (int d = 1; d < 1024; d <<= 1) {
        int u = (t >= d) ? s[t - d] : 0;
        __syncthreads();
        s[t] += u;
        __syncthreads();
    }
    if (t < nb) bsum[t] = s[t] - v;  // exclusive
}

// 2c) finalize: off = offtmp + block offset; nrm = rsqrt(max(deg,1))
__global__ __launch_bounds__(256) void k_scan3(const int* __restrict__ deg,
                                               const int* __restrict__ offtmp,
                                               const int* __restrict__ bsum, int n, int ne,
                                               int* __restrict__ off, float* __restrict__ nrm) {
    int i = blockIdx.x * 256 + threadIdx.x;
    if (i < n) {
        off[i] = offtmp[i] + bsum[blockIdx.x];
        nrm[i] = rsqrtf(fmaxf((float)deg[i], 1.0f));
    }
    if (i == 0) off[n] = ne;  // total edge count is known
}

// 3) atomic-free scatter: esrc[off[dst] + rank] = src
__global__ __launch_bounds__(256) void k_scatter(const int* __restrict__ src,
                                                 const int* __restrict__ dst,
                                                 const int* __restrict__ rank, int ne,
                                                 const int* __restrict__ off,
                                                 int* __restrict__ esrc) {
    int i = blockIdx.x * blockDim.x + threadIdx.x;
    if (i < ne) esrc[off[dst[i]] + rank[i]] = src[i];
}

// 4) wave-per-dst gather with src-side nrm folded in as fmaf:
//    out[d][c] = nrm[d] * sum_e nrm[esrc_e] * Yraw[esrc_e][c] + b[c]
__global__ __launch_bounds__(256) void k_agg(const int* __restrict__ off,
                                             const int* __restrict__ esrc,
                                             const float* __restrict__ Y,
                                             const float* __restrict__ nrm,
                                             const float* __restrict__ b,
                                             float* __restrict__ out, int n) {
    int wid = (int)((blockIdx.x * (size_t)blockDim.x + threadIdx.x) >> 6);
    if (wid >= n) return;
    int lane = threadIdx.x & 63;
    int g = lane >> 4;        // edge slot 0..3
    int c = (lane & 15) * 4;  // column base (16 lanes x float4 = full 64-col row)
    int s = off[wid];
    int e = off[wid + 1];
    float4 a0 = make_float4(0.f, 0.f, 0.f, 0.f);
    float4 a1 = make_float4(0.f, 0.f, 0.f, 0.f);
    int p = s + g;
    for (; p + 4 < e; p += 8) {
        int s0 = esrc[p];
        int s1 = esrc[p + 4];
        float f0 = nrm[s0];
        float f1 = nrm[s1];
        float4 r0 = *(const float4*)(Y + (size_t)s0 * N_CLS + c);
        float4 r1 = *(const float4*)(Y + (size_t)s1 * N_CLS + c);
        a0.x = fmaf(f0, r0.x, a0.x); a0.y = fmaf(f0, r0.y, a0.y);
        a0.z = fmaf(f0, r0.z, a0.z); a0.w = fmaf(f0, r0.w, a0.w);
        a1.x = fmaf(f1, r1.x, a1.x); a1.y = fmaf(f1, r1.y, a1.y);
        a1.z = fmaf(f1, r1.z, a1.z); a1.w = fmaf(f1, r1.w, a1.w);
    }
    if (p < e) {
        int s0 = esrc[p];
        float f0 = nrm[s0];
        float4 r0 = *(const float4*)(Y + (size_t)s0 * N_CLS + c);
        a0.x = fmaf(f0, r0.x, a0.x); a0.y = fmaf(f0, r0.y, a0.y);
        a0.z = fmaf(f0, r0.z, a0.z); a0.w = fmaf(f0, r0.w, a0.w);
    }
    a0.x += a1.x; a0.y += a1.y; a0.z += a1.z; a0.w += a1.w;
#pragma unroll
    for (int m = 16; m <= 32; m <<= 1) {
        a0.x += __shfl_xor(a0.x, m);
        a0.y += __shfl_xor(a0.y, m);
        a0.z += __shfl_xor(a0.z, m);
        a0.w += __shfl_xor(a0.w, m);
    }
    if (lane < 16) {
        float nv = nrm[wid];
        float4 bv = *(const float4*)(b + c);
        float4 o;
        o.x = a0.x * nv + bv.x;
        o.y = a0.y * nv + bv.y;
        o.z = a0.z * nv + bv.z;
        o.w = a0.w * nv + bv.w;
        *(float4*)(out + (size_t)wid * N_CLS + c) = o;
    }
}

extern "C" void kernel_launch(void* const* d_in, const int* in_sizes, int n_in,
                              void* d_out, int out_size, void* d_ws, size_t ws_size,
                              hipStream_t stream) {
    const float* X = (const float*)d_in[0];
    const float* W = (const float*)d_in[1];
    const float* b = (const float*)d_in[2];
    const int* src = (const int*)d_in[3];
    const int* dst = (const int*)d_in[4];
    int n = in_sizes[0] / N_FEAT;
    int ne = in_sizes[3];
    float* out = (float*)d_out;

    char* w = (char*)d_ws;
    auto take = [&](size_t bytes) {
        char* p = w;
        w += (bytes + 255) & ~(size_t)255;
        return p;
    };
    int nb = (n + 255) / 256;
    int* deg = (int*)take(((size_t)n + 4) * 4);  // padded to int4 multiple
    int* off = (int*)take((size_t)(n + 1) * 4);
    int* rank = (int*)take((size_t)ne * 4);
    int* offtmp = (int*)take((size_t)n * 4);
    int* bsum = (int*)take((size_t)1024 * 4);
    int* esrc = (int*)take((size_t)ne * 4);
    float* nrm = (float*)take((size_t)n * 4);
    float* Y = (float*)take((size_t)n * N_CLS * 4);

    const int tb = 256;
    int n4 = (n + 3) / 4;
    k_zero<<<(n4 + tb - 1) / tb, tb, 0, stream>>>((int4*)deg, n4);

    int gemm_blocks = (n + 63) / 64;                  // 782
    int rank_blocks = (ne + tb - 1) / tb;             // 3125
    k_gemm_rank<<<gemm_blocks + rank_blocks, tb, 0, stream>>>(X, W, Y, n, dst, ne, deg, rank,
                                                              gemm_blocks);

    k_scan1<<<nb, 256, 0, stream>>>(deg, n, offtmp, bsum);
    k_scan2<<<1, 1024, 0, stream>>>(bsum, nb);
    k_scan3<<<nb, 256, 0, stream>>>(deg, offtmp, bsum, n, ne, off, nrm);
    k_scatter<<<(ne + tb - 1) / tb, tb, 0, stream>>>(src, dst, rank, ne, off, esrc);
    long long total_threads = (long long)n * 64;
    k_agg<<<(int)((total_threads + tb - 1) / tb), tb, 0, stream>>>(off, esrc, Y, nrm, b, out, n);
}

// Round 12
// 109.165 us; speedup vs baseline: 6.7510x; 1.0334x over previous
//
#include <hip/hip_runtime.h>

#define N_FEAT 128
#define N_CLS 64
#define MAXD 96      // fixed bucket capacity; true max in-deg ~35 for this graph
#define DSTRIDE 16   // deg padded to one counter per 64B line

// 0) zero padded degree counters + overflow count
__global__ __launch_bounds__(256) void k_zero(int4* __restrict__ p, int n4,
                                              int* __restrict__ ovf_cnt) {
    int i = blockIdx.x * blockDim.x + threadIdx.x;
    for (; i < n4; i += gridDim.x * blockDim.x) p[i] = make_int4(0, 0, 0, 0);
    if (blockIdx.x == 0 && threadIdx.x == 0) *ovf_cnt = 0;
}

// 1) FUSED (roles interleaved mod-5 so both spread across all CUs):
//    GEMM blocks: Yraw = X @ W (wave-uniform W cols -> s_load K$ broadcast).
//    RANK blocks: p = atomicAdd(deg16[dst*16]); slot[dst*96+p] = src  (merges
//    the old scatter pass into the histogram; padded counters -> 1 line/node).
__global__ __launch_bounds__(256) void k_fused(
    const float* __restrict__ X, const float* __restrict__ W, float* __restrict__ Y, int n,
    const int* __restrict__ src, const int* __restrict__ dst, int ne,
    int* __restrict__ deg16, int* __restrict__ slot, int* __restrict__ ovf,
    int* __restrict__ ovf_cnt, int gemm_blocks, int f) {
    int bid = blockIdx.x;
    bool is_gemm = (bid % f == 0) && (bid / f < gemm_blocks);
    if (is_gemm) {
        int gb = bid / f;
        int lane = threadIdx.x & 63;
        int q = __builtin_amdgcn_readfirstlane(threadIdx.x >> 6);  // wave 0..3
        int cq = q * 16;
        int node = gb * 64 + lane;
        if (node >= n) return;

        float acc[16];
#pragma unroll
        for (int c = 0; c < 16; ++c) acc[c] = 0.f;

        const float* xrow = X + (size_t)node * N_FEAT;
        const float* wq = W + cq;
        for (int k4 = 0; k4 < N_FEAT; k4 += 4) {
            float4 xv = *(const float4*)(xrow + k4);
#pragma unroll
            for (int j = 0; j < 4; ++j) {
                float xj = (j == 0) ? xv.x : (j == 1) ? xv.y : (j == 2) ? xv.z : xv.w;
                const float* wrow = wq + (size_t)(k4 + j) * N_CLS;  // wave-uniform
#pragma unroll
                for (int c = 0; c < 16; c += 4) {
                    float4 wv = *(const float4*)(wrow + c);
                    acc[c + 0] = fmaf(xj, wv.x, acc[c + 0]);
                    acc[c + 1] = fmaf(xj, wv.y, acc[c + 1]);
                    acc[c + 2] = fmaf(xj, wv.z, acc[c + 2]);
                    acc[c + 3] = fmaf(xj, wv.w, acc[c + 3]);
                }
            }
        }

        float* yrow = Y + (size_t)node * N_CLS + cq;
#pragma unroll
        for (int c = 0; c < 16; c += 4) {
            float4 o;
            o.x = acc[c + 0]; o.y = acc[c + 1]; o.z = acc[c + 2]; o.w = acc[c + 3];
            *(float4*)(yrow + c) = o;
        }
    } else {
        int rb = bid - min(bid / f + 1, gemm_blocks);
        int i = rb * 256 + threadIdx.x;
        if (i < ne) {
            int d = dst[i];
            int p = atomicAdd(&deg16[d * DSTRIDE], 1);
            if (p < MAXD) {
                slot[(size_t)d * MAXD + p] = src[i];
            } else {
                int o = atomicAdd(ovf_cnt, 1);
                ovf[o] = i;  // never expected; correctness gutter
            }
        }
    }
}

// 2) nrm = rsqrt(max(deg,1))
__global__ __launch_bounds__(256) void k_nrm(const int* __restrict__ deg16, int n,
                                             float* __restrict__ nrm) {
    int i = blockIdx.x * 256 + threadIdx.x;
    if (i < n) nrm[i] = rsqrtf(fmaxf((float)deg16[i * DSTRIDE], 1.0f));
}

// 3) wave-per-dst gather over fixed-stride buckets:
//    out[d][c] = nrm[d] * sum_p nrm[slot_p] * Yraw[slot_p][c] + b[c]
__global__ __launch_bounds__(256) void k_agg(const int* __restrict__ deg16,
                                             const int* __restrict__ slot,
                                             const float* __restrict__ Y,
                                             const float* __restrict__ nrm,
                                             const float* __restrict__ b,
                                             float* __restrict__ out, int n) {
    int wid = (int)((blockIdx.x * (size_t)blockDim.x + threadIdx.x) >> 6);
    if (wid >= n) return;
    int lane = threadIdx.x & 63;
    int g = lane >> 4;        // edge slot 0..3
    int c = (lane & 15) * 4;  // column base (16 lanes x float4 = full 64-col row)
    int dcnt = min(deg16[wid * DSTRIDE], MAXD);
    int s = wid * MAXD;
    int e = s + dcnt;
    float4 a0 = make_float4(0.f, 0.f, 0.f, 0.f);
    float4 a1 = make_float4(0.f, 0.f, 0.f, 0.f);
    int p = s + g;
    for (; p + 4 < e; p += 8) {
        int s0 = slot[p];
        int s1 = slot[p + 4];
        float f0 = nrm[s0];
        float f1 = nrm[s1];
        float4 r0 = *(const float4*)(Y + (size_t)s0 * N_CLS + c);
        float4 r1 = *(const float4*)(Y + (size_t)s1 * N_CLS + c);
        a0.x = fmaf(f0, r0.x, a0.x); a0.y = fmaf(f0, r0.y, a0.y);
        a0.z = fmaf(f0, r0.z, a0.z); a0.w = fmaf(f0, r0.w, a0.w);
        a1.x = fmaf(f1, r1.x, a1.x); a1.y = fmaf(f1, r1.y, a1.y);
        a1.z = fmaf(f1, r1.z, a1.z); a1.w = fmaf(f1, r1.w, a1.w);
    }
    if (p < e) {
        int s0 = slot[p];
        float f0 = nrm[s0];
        float4 r0 = *(const float4*)(Y + (size_t)s0 * N_CLS + c);
        a0.x = fmaf(f0, r0.x, a0.x); a0.y = fmaf(f0, r0.y, a0.y);
        a0.z = fmaf(f0, r0.z, a0.z); a0.w = fmaf(f0, r0.w, a0.w);
    }
    a0.x += a1.x; a0.y += a1.y; a0.z += a1.z; a0.w += a1.w;
#pragma unroll
    for (int m = 16; m <= 32; m <<= 1) {
        a0.x += __shfl_xor(a0.x, m);
        a0.y += __shfl_xor(a0.y, m);
        a0.z += __shfl_xor(a0.z, m);
        a0.w += __shfl_xor(a0.w, m);
    }
    if (lane < 16) {
        float nv = nrm[wid];
        float4 bv = *(const float4*)(b + c);
        float4 o;
        o.x = a0.x * nv + bv.x;
        o.y = a0.y * nv + bv.y;
        o.z = a0.z * nv + bv.z;
        o.w = a0.w * nv + bv.w;
        *(float4*)(out + (size_t)wid * N_CLS + c) = o;
    }
}

// 4) overflow gutter (expected empty; single tiny block)
__global__ __launch_bounds__(64) void k_ovf(const int* __restrict__ ovf_cnt,
                                            const int* __restrict__ ovf,
                                            const int* __restrict__ src,
                                            const int* __restrict__ dst,
                                            const float* __restrict__ Y,
                                            const float* __restrict__ nrm,
                                            float* __restrict__ out) {
    int cnt = *ovf_cnt;
    for (int idx = 0; idx < cnt; ++idx) {
        int e = ovf[idx];
        int d = dst[e];
        int s = src[e];
        float f = nrm[d] * nrm[s];
        int c = threadIdx.x;  // 64 lanes = 64 cols
        atomicAdd(&out[(size_t)d * N_CLS + c], f * Y[(size_t)s * N_CLS + c]);
    }
}

extern "C" void kernel_launch(void* const* d_in, const int* in_sizes, int n_in,
                              void* d_out, int out_size, void* d_ws, size_t ws_size,
                              hipStream_t stream) {
    const float* X = (const float*)d_in[0];
    const float* W = (const float*)d_in[1];
    const float* b = (const float*)d_in[2];
    const int* src = (const int*)d_in[3];
    const int* dst = (const int*)d_in[4];
    int n = in_sizes[0] / N_FEAT;
    int ne = in_sizes[3];
    float* out = (float*)d_out;

    char* w = (char*)d_ws;
    auto take = [&](size_t bytes) {
        char* p = w;
        w += (bytes + 255) & ~(size_t)255;
        return p;
    };
    int* deg16 = (int*)take((size_t)n * DSTRIDE * 4);        // 3.2 MB padded counters
    int* slot = (int*)take((size_t)n * MAXD * 4);            // 19.2 MB buckets
    int* ovf = (int*)take((size_t)4096 * 4);
    int* ovf_cnt = (int*)take(256);
    float* nrm = (float*)take((size_t)n * 4);
    float* Y = (float*)take((size_t)n * N_CLS * 4);

    const int tb = 256;
    int n4 = (n * DSTRIDE) / 4;
    k_zero<<<1024, tb, 0, stream>>>((int4*)deg16, n4, ovf_cnt);

    int gemm_blocks = (n + 63) / 64;         // 782
    int rank_blocks = (ne + tb - 1) / tb;    // 3125
    int total = gemm_blocks + rank_blocks;   // 3907
    int f = (total + gemm_blocks - 1) / gemm_blocks;  // 5
    k_fused<<<total, tb, 0, stream>>>(X, W, Y, n, src, dst, ne, deg16, slot, ovf, ovf_cnt,
                                      gemm_blocks, f);

    k_nrm<<<(n + tb - 1) / tb, tb, 0, stream>>>(deg16, n, nrm);
    long long agg_threads = (long long)n * 64;
    k_agg<<<(int)((agg_threads + tb - 1) / tb), tb, 0, stream>>>(deg16, slot, Y, nrm, b, out, n);
    k_ovf<<<1, 64, 0, stream>>>(ovf_cnt, ovf, src, dst, Y, nrm, out);
}